// Round 8
// baseline (96.125 us; speedup 1.0000x reference)
//
#include <hip/hip_runtime.h>

#define H 4096
#define THREADS 256
#define ROWS 2
#define CHUNKS 4        // H / (THREADS * 4)
#define NCLUMP (H / 4)  // 1024 clumps of 4 d's

__device__ __forceinline__ unsigned pack_bf16(float a, float b) {
    unsigned ua = __float_as_uint(a), ub = __float_as_uint(b);
    ua = (ua + 0x7FFFu + ((ua >> 16) & 1u)) >> 16;
    ub = (ub + 0x7FFFu + ((ub >> 16) & 1u)) >> 16;
    return ua | (ub << 16);
}
__device__ __forceinline__ float unpack_lo(unsigned p) { return __uint_as_float(p << 16); }
__device__ __forceinline__ float unpack_hi(unsigned p) { return __uint_as_float(p & 0xFFFF0000u); }

// ---------- prep: block 0 computes C = A_v . B_q (4x4);
// ---------- blocks 1..8 pack A/B into clump-major bf16 ----------
// Apk[i*4+0] = Aq rows 0,1 for d=4i..4i+3 ; +1 = Aq rows 2,3 ; +2,+3 = Av.
// Bpk[i*4+0] = Bq d=4i,4i+1 (r0..3 each)  ; +1 = Bq d+2,d+3  ; +2,+3 = Bv.
__global__ void __launch_bounds__(THREADS) prep_kernel(
    const float* __restrict__ A_q, const float* __restrict__ B_q,
    const float* __restrict__ A_v, const float* __restrict__ B_v,
    float* __restrict__ C, uint4* __restrict__ Apk, uint4* __restrict__ Bpk)
{
    const int tid = threadIdx.x;
    if (blockIdx.x == 0) {
        float acc[4][4];
#pragma unroll
        for (int i = 0; i < 4; ++i)
#pragma unroll
            for (int j = 0; j < 4; ++j) acc[i][j] = 0.f;
#pragma unroll
        for (int c = 0; c < CHUNKS; ++c) {
            const int d0 = c * (THREADS * 4) + tid * 4;
            float avf[4][4], bqf[4][4];
#pragma unroll
            for (int r = 0; r < 4; ++r) {
                float4 t = *reinterpret_cast<const float4*>(A_v + (size_t)r * H + d0);
                avf[r][0] = t.x; avf[r][1] = t.y; avf[r][2] = t.z; avf[r][3] = t.w;
            }
#pragma unroll
            for (int i = 0; i < 4; ++i) {
                float4 t = *reinterpret_cast<const float4*>(B_q + (size_t)(d0 + i) * 4);
                bqf[i][0] = t.x; bqf[i][1] = t.y; bqf[i][2] = t.z; bqf[i][3] = t.w;
            }
#pragma unroll
            for (int i = 0; i < 4; ++i)
#pragma unroll
                for (int rp = 0; rp < 4; ++rp)
#pragma unroll
                    for (int r = 0; r < 4; ++r)
                        acc[rp][r] += avf[rp][i] * bqf[i][r];
        }
        const int lane = tid & 63, wave = tid >> 6;
        __shared__ float red[4][16];
#pragma unroll
        for (int rp = 0; rp < 4; ++rp)
#pragma unroll
            for (int r = 0; r < 4; ++r) {
                float v = acc[rp][r];
#pragma unroll
                for (int off = 32; off; off >>= 1) v += __shfl_down(v, off, 64);
                if (lane == 0) red[wave][rp * 4 + r] = v;
            }
        __syncthreads();
        if (tid < 16) C[tid] = red[0][tid] + red[1][tid] + red[2][tid] + red[3][tid];
        return;
    }

    const int g = (int)(blockIdx.x - 1) * THREADS + tid;   // 0..2047
    if (g < NCLUMP) {                                      // pack A clump g
        const int d0 = g * 4;
        uint4 w[4];
#pragma unroll
        for (int j = 0; j < 2; ++j) {
            const float* src = j ? A_v : A_q;
#pragma unroll
            for (int p = 0; p < 2; ++p) {
                float4 r0 = *reinterpret_cast<const float4*>(src + (size_t)(2 * p) * H + d0);
                float4 r1 = *reinterpret_cast<const float4*>(src + (size_t)(2 * p + 1) * H + d0);
                w[j * 2 + p] = make_uint4(pack_bf16(r0.x, r0.y), pack_bf16(r0.z, r0.w),
                                          pack_bf16(r1.x, r1.y), pack_bf16(r1.z, r1.w));
            }
        }
#pragma unroll
        for (int j = 0; j < 4; ++j) Apk[g * 4 + j] = w[j];
    } else if (g < 2 * NCLUMP) {                           // pack B clump
        const int i = g - NCLUMP;
        const int d0 = i * 4;
        uint4 w[4];
#pragma unroll
        for (int j = 0; j < 2; ++j) {
            const float* src = j ? B_v : B_q;
#pragma unroll
            for (int p = 0; p < 2; ++p) {
                float4 e0 = *reinterpret_cast<const float4*>(src + (size_t)(d0 + 2 * p) * 4);
                float4 e1 = *reinterpret_cast<const float4*>(src + (size_t)(d0 + 2 * p + 1) * 4);
                w[j * 2 + p] = make_uint4(pack_bf16(e0.x, e0.y), pack_bf16(e0.z, e0.w),
                                          pack_bf16(e1.x, e1.y), pack_bf16(e1.z, e1.w));
            }
        }
#pragma unroll
        for (int j = 0; j < 4; ++j) Bpk[i * 4 + j] = w[j];
    }
}

// Accumulate one uint4 (two rank-rows, 4 d's) into acc slots rb, rb+1.
#define ACC_PAIR(q, acc, rb)                                                  \
    {                                                                         \
        float f0 = unpack_lo((q).x), f1 = unpack_hi((q).x);                   \
        float f2 = unpack_lo((q).y), f3 = unpack_hi((q).y);                   \
        acc[0][rb] += xv0.x * f0 + xv0.y * f1 + xv0.z * f2 + xv0.w * f3;      \
        acc[1][rb] += xv1.x * f0 + xv1.y * f1 + xv1.z * f2 + xv1.w * f3;      \
        f0 = unpack_lo((q).z); f1 = unpack_hi((q).z);                         \
        f2 = unpack_lo((q).w); f3 = unpack_hi((q).w);                         \
        acc[0][rb + 1] += xv0.x * f0 + xv0.y * f1 + xv0.z * f2 + xv0.w * f3;  \
        acc[1][rb + 1] += xv1.x * f0 + xv1.y * f1 + xv1.z * f2 + xv1.w * f3;  \
    }

// ---------- fused kernel: bf16 operands, x in LDS, unroll-1 loops ----------
__global__ void __launch_bounds__(THREADS) lora_fused_kernel(
    const float* __restrict__ x,
    const uint4* __restrict__ Apk, const uint4* __restrict__ Bpk,
    const float* __restrict__ C,
    float* __restrict__ out)
{
    const int tid = threadIdx.x;
    const size_t row0 = (size_t)blockIdx.x * ROWS;
    const float* xbase = x + row0 * H;

    __shared__ uint2 xlds[ROWS][NCLUMP];   // bf16-packed x: 8 KB/row
    __shared__ float red[4][16];
    __shared__ float sums[16];

    float accq[ROWS][4], accv[ROWS][4];
#pragma unroll
    for (int m = 0; m < ROWS; ++m)
#pragma unroll
        for (int r = 0; r < 4; ++r) { accq[m][r] = 0.f; accv[m][r] = 0.f; }

    // ---- Phase 1: rank-4 projections; park packed x in LDS ----
#pragma unroll 1
    for (int c = 0; c < CHUNKS; ++c) {
        const int idx = c * THREADS + tid;
        const float4 xv0 = *reinterpret_cast<const float4*>(xbase + (size_t)idx * 4);
        const float4 xv1 = *reinterpret_cast<const float4*>(xbase + H + (size_t)idx * 4);
        xlds[0][idx] = make_uint2(pack_bf16(xv0.x, xv0.y), pack_bf16(xv0.z, xv0.w));
        xlds[1][idx] = make_uint2(pack_bf16(xv1.x, xv1.y), pack_bf16(xv1.z, xv1.w));
        const uint4* ap = Apk + (size_t)idx * 4;
        const uint4 a0 = ap[0], a1 = ap[1], a2 = ap[2], a3 = ap[3];
        ACC_PAIR(a0, accq, 0)
        ACC_PAIR(a1, accq, 2)
        ACC_PAIR(a2, accv, 0)
        ACC_PAIR(a3, accv, 2)
    }

    // ---- Block reduction: 16 values (idx = m*8 + v; v<4 accq, v>=4 accv) ----
    const int lane = tid & 63, wave = tid >> 6;
#pragma unroll
    for (int i = 0; i < 16; ++i) {
        const int m = i >> 3, v = i & 7;
        float s = (v < 4) ? accq[m][v] : accv[m][v - 4];
#pragma unroll
        for (int off = 1; off < 64; off <<= 1) s += __shfl_xor(s, off, 64);
        if (lane == 0) red[wave][i] = s;
    }
    __syncthreads();
    if (tid < 16) sums[tid] = red[0][tid] + red[1][tid] + red[2][tid] + red[3][tid];
    __syncthreads();

    // lq2 = 2*lq ; lv2 = 2*(lowx_v + 2*lq.C^T)
    float lq2[ROWS][4], lv2[ROWS][4];
    {
        float cm[16];
#pragma unroll
        for (int i = 0; i < 16; ++i) cm[i] = C[i];
#pragma unroll
        for (int m = 0; m < ROWS; ++m) {
#pragma unroll
            for (int r = 0; r < 4; ++r) lq2[m][r] = 2.f * sums[m * 8 + r];
#pragma unroll
            for (int rp = 0; rp < 4; ++rp) {
                float s = sums[m * 8 + 4 + rp];
#pragma unroll
                for (int r = 0; r < 4; ++r) s += sums[m * 8 + r] * 2.f * cm[rp * 4 + r];
                lv2[m][rp] = 2.f * s;
            }
        }
    }

    // ---- Phase 2: out = 2*x + lq2.Bq[d] + lv2.Bv[d] ----
#pragma unroll 1
    for (int c = 0; c < CHUNKS; ++c) {
        const int idx = c * THREADS + tid;
        const uint4* bp = Bpk + (size_t)idx * 4;
        const uint4 b0 = bp[0], b1 = bp[1], b2 = bp[2], b3 = bp[3];
        const uint2 xp0 = xlds[0][idx], xp1 = xlds[1][idx];
        float o0[4], o1[4];
#pragma unroll
        for (int k = 0; k < 4; ++k) {
            const unsigned wq0 = (k == 0) ? b0.x : (k == 1) ? b0.z : (k == 2) ? b1.x : b1.z;
            const unsigned wq1 = (k == 0) ? b0.y : (k == 1) ? b0.w : (k == 2) ? b1.y : b1.w;
            const unsigned wv0 = (k == 0) ? b2.x : (k == 1) ? b2.z : (k == 2) ? b3.x : b3.z;
            const unsigned wv1 = (k == 0) ? b2.y : (k == 1) ? b2.w : (k == 2) ? b3.y : b3.w;
            const unsigned xw0 = (k < 2) ? xp0.x : xp0.y;
            const unsigned xw1 = (k < 2) ? xp1.x : xp1.y;
            const float xs0 = (k & 1) ? unpack_hi(xw0) : unpack_lo(xw0);
            const float xs1 = (k & 1) ? unpack_hi(xw1) : unpack_lo(xw1);
            const float q0 = unpack_lo(wq0), q1 = unpack_hi(wq0), q2 = unpack_lo(wq1), q3 = unpack_hi(wq1);
            const float v0 = unpack_lo(wv0), v1 = unpack_hi(wv0), v2 = unpack_lo(wv1), v3 = unpack_hi(wv1);
            o0[k] = 2.f * xs0 + lq2[0][0] * q0 + lq2[0][1] * q1 + lq2[0][2] * q2 + lq2[0][3] * q3
                              + lv2[0][0] * v0 + lv2[0][1] * v1 + lv2[0][2] * v2 + lv2[0][3] * v3;
            o1[k] = 2.f * xs1 + lq2[1][0] * q0 + lq2[1][1] * q1 + lq2[1][2] * q2 + lq2[1][3] * q3
                              + lv2[1][0] * v0 + lv2[1][1] * v1 + lv2[1][2] * v2 + lv2[1][3] * v3;
        }
        *reinterpret_cast<float4*>(out + row0 * H + (size_t)idx * 4) =
            make_float4(o0[0], o0[1], o0[2], o0[3]);
        *reinterpret_cast<float4*>(out + (row0 + 1) * H + (size_t)idx * 4) =
            make_float4(o1[0], o1[1], o1[2], o1[3]);
    }
}

extern "C" void kernel_launch(void* const* d_in, const int* in_sizes, int n_in,
                              void* d_out, int out_size, void* d_ws, size_t ws_size,
                              hipStream_t stream) {
    const float* x   = (const float*)d_in[0];
    const float* A_q = (const float*)d_in[1];
    const float* B_q = (const float*)d_in[2];
    const float* A_v = (const float*)d_in[3];
    const float* B_v = (const float*)d_in[4];
    float* out = (float*)d_out;

    float* C   = (float*)d_ws;                                   // 64 B
    uint4* Apk = (uint4*)((char*)d_ws + 256);                    // 64 KB
    uint4* Bpk = (uint4*)((char*)d_ws + 256 + 64 * 1024);        // 64 KB

    const int nrows = in_sizes[0] / H;  // B*S = 8192

    prep_kernel<<<9, THREADS, 0, stream>>>(A_q, B_q, A_v, B_v, C, Apk, Bpk);
    lora_fused_kernel<<<nrows / ROWS, THREADS, 0, stream>>>(x, Apk, Bpk, C, out);
}